// Round 10
// baseline (144.599 us; speedup 1.0000x reference)
//
#include <hip/hip_runtime.h>
#include <math.h>

// Causal flash attention, B=2 H=16 S=2048 D=64, fp32 in/out, bf16 MFMA compute.
// R15: traffic-halving. Each wave owns an ADJACENT set-pair (2p,2p+1): one
// kf/vf fragment load (8KB) feeds QK+PV for both q-sets (2x arith intensity;
// K/V L2 traffic 532->270 MB). Block = pair-pair (pp,31-pp) = 66 load-units,
// chunked 4 ways (16-17/wave, uniform), R13 two-phase transition, dumps carry
// 2 sets/slot. Even set's beyond-diag unit computed fully-masked (exp2(-1e30)
// = 0) -> branch-free. Qf buffer DELETED: fattn reads fp32 Q directly (same
// scale+RNE convert); prep converts K/V only (75->50 MB).
// Carried: coalesced frag buffers, zero-sync loop + ONE __syncthreads,
// in-block combine, final fp32 O direct, P pack via v_perm, permlane32_swap
// P-exchange, persistent zero-C, setprio(1) on MFMA clusters.

constexpr int kS   = 2048;
constexpr int kD   = 64;
constexpr int kBH  = 32;
constexpr int kPadP = 72;           // prep-kernel LDS pad only
constexpr int kFragBH = 64 * 4 * 512;   // u16 per bh per buffer: 64 units x 4 chunks x 512

typedef short short8 __attribute__((ext_vector_type(8)));
typedef float float4v __attribute__((ext_vector_type(4)));
typedef float float16v __attribute__((ext_vector_type(16)));
typedef unsigned int u32;
typedef unsigned short u16;

static __device__ inline u16 f2bf(float f) {
  union { float f; unsigned u; } v; v.f = f;
  unsigned r = v.u + 0x7FFF + ((v.u >> 16) & 1);   // RNE
  return (u16)(r >> 16);
}

static __device__ inline short8 pack8(float4v a, float4v b) {
  short8 r;
  r[0] = (short)f2bf(a[0]); r[1] = (short)f2bf(a[1]);
  r[2] = (short)f2bf(a[2]); r[3] = (short)f2bf(a[3]);
  r[4] = (short)f2bf(b[0]); r[5] = (short)f2bf(b[1]);
  r[6] = (short)f2bf(b[2]); r[7] = (short)f2bf(b[3]);
  return r;
}

// half-swap: v_permlane32_swap_b32 A, B : A.hi-lanes <-> B.lo-lanes
static __device__ inline void swap32(u32 a, u32 b, u32& oa, u32& ob) {
#if __has_builtin(__builtin_amdgcn_permlane32_swap)
  auto r = __builtin_amdgcn_permlane32_swap(a, b, false, false);
  oa = r[0]; ob = r[1];
#else
  asm volatile("v_permlane32_swap_b32 %0, %1" : "+v"(a), "+v"(b));
  oa = a; ob = b;
#endif
}

// ---- prepass: K/V only -> fragment-order buffers ----
// Kf chunk(unit u, dk, lane): elem = K[row u*32 + (lane&31)][dk*16 + (lane>>5)*8 .. +8]
// Vf chunk(unit u, c, lane): elem = V^T[d = (c&1)*32 + (lane&31)][key u*32 + (c>>1)*16 + (lane>>5)*8 .. +8]
__global__ __launch_bounds__(256)
void prep_kernel(const float* __restrict__ K, const float* __restrict__ V,
                 u16* __restrict__ Kf, u16* __restrict__ Vf) {
  __shared__ u16 tile[64 * kPadP];
  const int tid = threadIdx.x;
  const int bh = blockIdx.y, st = blockIdx.x;
  const size_t ibase = (size_t)bh * kS * kD + (size_t)st * 64 * kD;
  const size_t fbase = (size_t)bh * kFragBH;
  const int r  = tid >> 2;        // row within 64-row tile
  const int c0 = (tid & 3) * 16;  // col start
  const int dk = tid & 3;
  const int U  = st * 2 + (r >> 5);   // global 32-row unit index
  const int lr = r & 31;
  {
    const float* kp = K + ibase + (size_t)r * kD + c0;
    float4v a = *(const float4v*)(kp);
    float4v b = *(const float4v*)(kp + 4);
    float4v c = *(const float4v*)(kp + 8);
    float4v d = *(const float4v*)(kp + 12);
    u16* dst = Kf + fbase + (size_t)(U * 4 + dk) * 512;
    *(short8*)(dst + lr * 8)        = pack8(a, b);   // h=0 chunk
    *(short8*)(dst + (32 + lr) * 8) = pack8(c, d);   // h=1 chunk
  }
  {
    const float* vp = V + ibase + (size_t)r * kD + c0;
    float4v a = *(const float4v*)(vp);
    float4v b = *(const float4v*)(vp + 4);
    float4v c = *(const float4v*)(vp + 8);
    float4v d = *(const float4v*)(vp + 12);
    u16* t = &tile[r * kPadP + c0];
    *(short8*)t       = pack8(a, b);
    *(short8*)(t + 8) = pack8(c, d);
  }
  __syncthreads();
  {
    const int dd = tid >> 2;          // d-row of V^T
    const int s0 = (tid & 3) * 16;    // key col start within tile
    short8 w0, w1;
    #pragma unroll
    for (int i = 0; i < 8; ++i) {
      w0[i] = (short)tile[(s0 + i) * kPadP + dd];
      w1[i] = (short)tile[(s0 + 8 + i) * kPadP + dd];
    }
    const int ku   = st * 2 + (s0 >> 5);        // unit index
    const int koff = s0 & 31;                   // 0 or 16
    const int c    = ((koff >> 4) << 1) | (dd >> 5);
    u16* vdst = Vf + fbase + (size_t)(ku * 4 + c) * 512;
    *(short8*)(vdst + (dd & 31) * 8)        = w0;   // h=0 (key +0..7)
    *(short8*)(vdst + (32 + (dd & 31)) * 8) = w1;   // h=1 (key +8..15)
  }
}

// ---- main flash kernel: paired-set zero-sync loop, in-block combine ----
__global__ __launch_bounds__(256, 2)
void fattn_kernel(const float* __restrict__ Qp, const u16* __restrict__ Kf,
                  const u16* __restrict__ Vf, float* __restrict__ O) {
  __shared__ u32   ldsP[5][2][32][33];   // [slot][set01][q-row][packed d,d+32]
  __shared__ float ldsL[5][2][32];

  const int tid  = threadIdx.x;
  const int wave = tid >> 6;
  const int lane = tid & 63;
  const int l31  = lane & 31;
  const int h    = lane >> 5;

  // 512 blocks: xcd=blk&7 hosts bh {4x..4x+3}; pair-pair index pp = blk>>5
  const int blk = blockIdx.x;
  const int bh  = (blk & 7) * 4 + ((blk >> 3) & 3);
  const int pp  = blk >> 5;          // 0..15: pairs pp and 31-pp
  const int tP  = 2 * pp + 2;        // units of pair pp; boundary in [2,32]
  const int lo  = (66 * wave) >> 2;  // 0,16,33,49
  const int hi  = (66 * (wave + 1)) >> 2;   // 16,33,49,66
  const int uT  = min(max(tP, lo), hi);     // phase1 [lo,uT) pair pp; phase2 [uT,hi)

  const u16* gk = Kf + (size_t)bh * kFragBH + lane * 8;   // + k*2048 + dk*512
  const u16* gv = Vf + (size_t)bh * kFragBH + lane * 8;   // + k*2048 + c*512

  float16v zf;
  #pragma unroll
  for (int i = 0; i < 16; ++i) zf[i] = 0.f;

  float16v acc00 = zf, acc01 = zf, acc10 = zf, acc11 = zf;
  float lac0 = 0.f, lac1 = 0.f;
  short8 qf0[4], qf1[4];

  // direct fp32 Q read + scale + RNE convert (identical math to old prepass)
  auto loadQ = [&](int s, short8* qf) {
    const float scl = 0.125f * 1.44269504089f;   // 1/sqrt(64) * log2(e)
    const float* qp = Qp + ((size_t)bh * kS + (size_t)(s * 32 + l31)) * kD + h * 8;
    #pragma unroll
    for (int dk = 0; dk < 4; ++dk) {
      float4v a = *(const float4v*)(qp + dk * 16);
      float4v b = *(const float4v*)(qp + dk * 16 + 4);
      #pragma unroll
      for (int i = 0; i < 4; ++i) { a[i] *= scl; b[i] *= scl; }
      qf[dk] = pack8(a, b);
    }
  };

  // one set's QK -> mask -> softmax -> PV for unit k (kf/vf shared by pair)
  auto process = [&](const short8* qf, float16v& a0, float16v& a1, float& lac,
                     int sdiag, int k, const short8* kf, const short8* vf) {
    __builtin_amdgcn_s_setprio(1);
    float16v sv = __builtin_amdgcn_mfma_f32_32x32x16_bf16(kf[0], qf[0], zf, 0, 0, 0);
    sv = __builtin_amdgcn_mfma_f32_32x32x16_bf16(kf[1], qf[1], sv, 0, 0, 0);
    sv = __builtin_amdgcn_mfma_f32_32x32x16_bf16(kf[2], qf[2], sv, 0, 0, 0);
    sv = __builtin_amdgcn_mfma_f32_32x32x16_bf16(kf[3], qf[3], sv, 0, 0, 0);
    __builtin_amdgcn_s_setprio(0);

    if (k >= sdiag) {   // diagonal (k==sdiag) or fully-masked (k>sdiag) unit
      const int qg = sdiag * 32 + l31;
      #pragma unroll
      for (int r = 0; r < 16; ++r) {
        const int kg = k * 32 + (r & 3) + 8 * (r >> 2) + 4 * h;
        if (kg > qg) sv[r] = -1e30f;
      }
    }

    u32 pk[8];
    #pragma unroll
    for (int g2 = 0; g2 < 4; ++g2) {
      const u32 u0 = __float_as_uint(__builtin_amdgcn_exp2f(sv[4 * g2 + 0]));
      const u32 u1 = __float_as_uint(__builtin_amdgcn_exp2f(sv[4 * g2 + 1]));
      const u32 u2 = __float_as_uint(__builtin_amdgcn_exp2f(sv[4 * g2 + 2]));
      const u32 u3 = __float_as_uint(__builtin_amdgcn_exp2f(sv[4 * g2 + 3]));
      pk[2 * g2]     = __builtin_amdgcn_perm(u1, u0, 0x07060302u);
      pk[2 * g2 + 1] = __builtin_amdgcn_perm(u3, u2, 0x07060302u);
    }

    // l partial: 2-acc sum of this lane's 16 bf16-truncated P values
    {
      float e0 = 0.f, e1 = 0.f;
      #pragma unroll
      for (int i = 0; i < 4; ++i) {
        e0 += __uint_as_float(pk[i] << 16)     + __uint_as_float(pk[i] & 0xFFFF0000u);
        e1 += __uint_as_float(pk[i + 4] << 16) + __uint_as_float(pk[i + 4] & 0xFFFF0000u);
      }
      lac += e0 + e1;
    }

    union { u32 u[4]; short8 s8; } pf;
    swap32(pk[0], pk[2], pf.u[0], pf.u[2]);
    swap32(pk[1], pk[3], pf.u[1], pf.u[3]);
    __builtin_amdgcn_s_setprio(1);
    a0 = __builtin_amdgcn_mfma_f32_32x32x16_bf16(pf.s8, vf[0], a0, 0, 0, 0);
    a1 = __builtin_amdgcn_mfma_f32_32x32x16_bf16(pf.s8, vf[1], a1, 0, 0, 0);
    __builtin_amdgcn_s_setprio(0);
    swap32(pk[4], pk[6], pf.u[0], pf.u[2]);
    swap32(pk[5], pk[7], pf.u[1], pf.u[3]);
    __builtin_amdgcn_s_setprio(1);
    a0 = __builtin_amdgcn_mfma_f32_32x32x16_bf16(pf.s8, vf[2], a0, 0, 0, 0);
    a1 = __builtin_amdgcn_mfma_f32_32x32x16_bf16(pf.s8, vf[3], a1, 0, 0, 0);
    __builtin_amdgcn_s_setprio(0);
  };

  // one 32-key unit: load kf/vf once, compute BOTH sets of the pair
  auto unit = [&](int k, int s0, int s1) {
    const u16* kp = gk + (size_t)k * 2048;
    const u16* vp = gv + (size_t)k * 2048;
    short8 kf[4], vf[4];
    #pragma unroll
    for (int i = 0; i < 4; ++i) kf[i] = *(const short8*)(kp + i * 512);
    #pragma unroll
    for (int i = 0; i < 4; ++i) vf[i] = *(const short8*)(vp + i * 512);
    process(qf0, acc00, acc01, lac0, s0, k, kf, vf);
    process(qf1, acc10, acc11, lac1, s1, k, kf, vf);
  };

  auto runPhase = [&](int p, int kb, int ke) {
    loadQ(2 * p,     qf0);
    loadQ(2 * p + 1, qf1);
    for (int k = kb; k < ke; ++k) unit(k, 2 * p, 2 * p + 1);
  };

  auto dump = [&](int slot) {
    #pragma unroll
    for (int r = 0; r < 16; ++r) {
      const int row = (r & 3) + 8 * (r >> 2) + 4 * h;
      ldsP[slot][0][row][l31] = (u32)f2bf(acc00[r]) | ((u32)f2bf(acc01[r]) << 16);
      ldsP[slot][1][row][l31] = (u32)f2bf(acc10[r]) | ((u32)f2bf(acc11[r]) << 16);
    }
    const float lt0 = lac0 + __shfl_xor(lac0, 32);
    const float lt1 = lac1 + __shfl_xor(lac1, 32);
    if (lane < 32) { ldsL[slot][0][lane] = lt0; ldsL[slot][1][lane] = lt1; }
  };

  // ---- phase 1: pair pp, units [lo, uT), k = u ----
  if (lo < uT) {
    runPhase(pp, lo, uT);
    dump(wave);
    acc00 = zf; acc01 = zf; acc10 = zf; acc11 = zf; lac0 = 0.f; lac1 = 0.f;
  }
  // ---- phase 2: pair 31-pp, units [uT, hi), k = u - tP ----
  if (uT < hi) {
    runPhase(31 - pp, uT - tP, hi - tP);
    dump((lo < uT) ? 4 : wave);
  }

  __syncthreads();

  // ---- in-block reduce: 4 sets x 32 q x 64 d ----
  {
    const int sid     = tid >> 6;        // 0..3
    const int pairSel = sid >> 1;        // 0 => pair pp, 1 => pair 31-pp
    const int set01   = sid & 1;
    const int sOut    = pairSel ? (62 - 2 * pp + set01) : (2 * pp + set01);
    const int j  = tid & 63;
    const int q  = j >> 1;
    const int c0 = (j & 1) * 16;

    // slot validity (chunk lows 0,16,33,49; tP in [2,32]):
    // pair pp: slot0 always; slot1 iff tP>16. pair 31-pp: slot1 iff tP<=16;
    // slots 2,3 always; slot4 (transition, always pair 31-pp) iff tP!=16.
    bool v[5];
    if (pairSel == 0) { v[0] = true;  v[1] = (tP > 16);  v[2] = false; v[3] = false; v[4] = false; }
    else              { v[0] = false; v[1] = (tP <= 16); v[2] = true;  v[3] = true;  v[4] = (tP != 16); }

    float lsum = 0.f;
    #pragma unroll
    for (int s = 0; s < 5; ++s) if (v[s]) lsum += ldsL[s][set01][q];
    const float inv = 1.f / lsum;

    float* op = O + ((size_t)bh * kS + (size_t)(sOut * 32 + q)) * kD;
    #pragma unroll
    for (int i = 0; i < 16; ++i) {
      const int c = c0 + i;
      float lov = 0.f, hiv = 0.f;
      #pragma unroll
      for (int s = 0; s < 5; ++s) if (v[s]) {
        const u32 p = ldsP[s][set01][q][c];
        lov += __uint_as_float(p << 16);
        hiv += __uint_as_float(p & 0xFFFF0000u);
      }
      op[c]      = lov * inv;
      op[c + 32] = hiv * inv;
    }
  }
}

extern "C" void kernel_launch(void* const* d_in, const int* in_sizes, int n_in,
                              void* d_out, int out_size, void* d_ws, size_t ws_size,
                              hipStream_t stream) {
  const float* Q = (const float*)d_in[0];
  const float* K = (const float*)d_in[1];
  const float* V = (const float*)d_in[2];
  float* O = (float*)d_out;

  const size_t nKV = (size_t)kBH * kS * kD;      // 4.19M elems
  u16* Kf = (u16*)d_ws;                          // 8.39 MB
  u16* Vf = Kf + nKV;                            // 8.39 MB

  dim3 gprep(kS / 64, kBH);
  prep_kernel<<<gprep, 256, 0, stream>>>(K, V, Kf, Vf);
  fattn_kernel<<<512, 256, 0, stream>>>(Q, Kf, Vf, O);
}

// Round 11
// 135.874 us; speedup vs baseline: 1.0642x; 1.0642x over previous
//
#include <hip/hip_runtime.h>
#include <math.h>

// Causal flash attention, B=2 H=16 S=2048 D=64, fp32 in/out, bf16 MFMA compute.
// R16: R12-best structure (two-phase uniform waves, grid 1024, bounds(256,3))
// with Qf buffer DELETED: fattn reads fp32 Q directly (R15-proven safe, same
// scale+RNE), prep converts K/V only (75->50 MB, ~-4us). Everything else =
// R12/R13: 4096 uniform waves (block = pair (sA,63-sA), 65 units chunked 4
// ways), zero-sync loop, coalesced frag buffers (FETCH ~17MB, 0 conflicts),
// in-block combine via 5 bf16-packed LDS slots + ONE __syncthreads, final
// fp32 O direct. Carried: P pack via v_perm, permlane32_swap P-exchange,
// persistent zero-C, setprio(1) on MFMA clusters.
// Session law (R7..R15): fattn time tracks resident waves/CU, saturating
// ~40us at 12-16 waves/CU; occupancy/ILP/vmcnt/traffic levers each falsified.

constexpr int kS   = 2048;
constexpr int kD   = 64;
constexpr int kBH  = 32;
constexpr int kPadP = 72;           // prep-kernel LDS pad only
constexpr int kFragBH = 64 * 4 * 512;   // u16 per bh per buffer: 64 units x 4 chunks x 512

typedef short short8 __attribute__((ext_vector_type(8)));
typedef float float4v __attribute__((ext_vector_type(4)));
typedef float float16v __attribute__((ext_vector_type(16)));
typedef unsigned int u32;
typedef unsigned short u16;

static __device__ inline u16 f2bf(float f) {
  union { float f; unsigned u; } v; v.f = f;
  unsigned r = v.u + 0x7FFF + ((v.u >> 16) & 1);   // RNE
  return (u16)(r >> 16);
}

static __device__ inline short8 pack8(float4v a, float4v b) {
  short8 r;
  r[0] = (short)f2bf(a[0]); r[1] = (short)f2bf(a[1]);
  r[2] = (short)f2bf(a[2]); r[3] = (short)f2bf(a[3]);
  r[4] = (short)f2bf(b[0]); r[5] = (short)f2bf(b[1]);
  r[6] = (short)f2bf(b[2]); r[7] = (short)f2bf(b[3]);
  return r;
}

// half-swap: v_permlane32_swap_b32 A, B : A.hi-lanes <-> B.lo-lanes
static __device__ inline void swap32(u32 a, u32 b, u32& oa, u32& ob) {
#if __has_builtin(__builtin_amdgcn_permlane32_swap)
  auto r = __builtin_amdgcn_permlane32_swap(a, b, false, false);
  oa = r[0]; ob = r[1];
#else
  asm volatile("v_permlane32_swap_b32 %0, %1" : "+v"(a), "+v"(b));
  oa = a; ob = b;
#endif
}

// ---- prepass: K/V only -> fragment-order buffers ----
// Kf chunk(unit u, dk, lane): elem = K[row u*32 + (lane&31)][dk*16 + (lane>>5)*8 .. +8]
// Vf chunk(unit u, c, lane): elem = V^T[d = (c&1)*32 + (lane&31)][key u*32 + (c>>1)*16 + (lane>>5)*8 .. +8]
__global__ __launch_bounds__(256)
void prep_kernel(const float* __restrict__ K, const float* __restrict__ V,
                 u16* __restrict__ Kf, u16* __restrict__ Vf) {
  __shared__ u16 tile[64 * kPadP];
  const int tid = threadIdx.x;
  const int bh = blockIdx.y, st = blockIdx.x;
  const size_t ibase = (size_t)bh * kS * kD + (size_t)st * 64 * kD;
  const size_t fbase = (size_t)bh * kFragBH;
  const int r  = tid >> 2;        // row within 64-row tile
  const int c0 = (tid & 3) * 16;  // col start
  const int dk = tid & 3;
  const int U  = st * 2 + (r >> 5);   // global 32-row unit index
  const int lr = r & 31;
  {
    const float* kp = K + ibase + (size_t)r * kD + c0;
    float4v a = *(const float4v*)(kp);
    float4v b = *(const float4v*)(kp + 4);
    float4v c = *(const float4v*)(kp + 8);
    float4v d = *(const float4v*)(kp + 12);
    u16* dst = Kf + fbase + (size_t)(U * 4 + dk) * 512;
    *(short8*)(dst + lr * 8)        = pack8(a, b);   // h=0 chunk
    *(short8*)(dst + (32 + lr) * 8) = pack8(c, d);   // h=1 chunk
  }
  {
    const float* vp = V + ibase + (size_t)r * kD + c0;
    float4v a = *(const float4v*)(vp);
    float4v b = *(const float4v*)(vp + 4);
    float4v c = *(const float4v*)(vp + 8);
    float4v d = *(const float4v*)(vp + 12);
    u16* t = &tile[r * kPadP + c0];
    *(short8*)t       = pack8(a, b);
    *(short8*)(t + 8) = pack8(c, d);
  }
  __syncthreads();
  {
    const int dd = tid >> 2;          // d-row of V^T
    const int s0 = (tid & 3) * 16;    // key col start within tile
    short8 w0, w1;
    #pragma unroll
    for (int i = 0; i < 8; ++i) {
      w0[i] = (short)tile[(s0 + i) * kPadP + dd];
      w1[i] = (short)tile[(s0 + 8 + i) * kPadP + dd];
    }
    const int ku   = st * 2 + (s0 >> 5);        // unit index
    const int koff = s0 & 31;                   // 0 or 16
    const int c    = ((koff >> 4) << 1) | (dd >> 5);
    u16* vdst = Vf + fbase + (size_t)(ku * 4 + c) * 512;
    *(short8*)(vdst + (dd & 31) * 8)        = w0;   // h=0 (key +0..7)
    *(short8*)(vdst + (32 + (dd & 31)) * 8) = w1;   // h=1 (key +8..15)
  }
}

// ---- main flash kernel: zero-sync two-phase loop, in-block combine ----
__global__ __launch_bounds__(256, 3)
void fattn_kernel(const float* __restrict__ Qp, const u16* __restrict__ Kf,
                  const u16* __restrict__ Vf, float* __restrict__ O) {
  __shared__ u32   ldsP[5][32][33];   // bf16-pair packed partials (padded)
  __shared__ float ldsL[5][32];

  const int tid  = threadIdx.x;
  const int wave = tid >> 6;
  const int lane = tid & 63;
  const int l31  = lane & 31;
  const int h    = lane >> 5;

  // 1024 blocks: xcd=blk&7 hosts bh {4x..4x+3}; pair index = blk>>5
  const int blk = blockIdx.x;
  const int bh  = (blk & 7) * 4 + ((blk >> 3) & 3);
  const int sA  = blk >> 5;          // 0..31 (small set)
  const int sB  = 63 - sA;           // 32..63 (large set)
  const int t   = sB + 1;            // first A-unit in concatenated range [0,65)
  const int lo  = (65 * wave) >> 2;  // 0,16,32,48
  const int hi  = (65 * (wave + 1)) >> 2;   // 16,32,48,65
  const int uT  = min(max(t, lo), hi);      // B phase: [lo,uT), A phase: [uT,hi)

  const u16* gk = Kf + (size_t)bh * kFragBH + lane * 8;   // + k*2048 + dk*512
  const u16* gv = Vf + (size_t)bh * kFragBH + lane * 8;   // + k*2048 + c*512

  float16v zf;
  #pragma unroll
  for (int i = 0; i < 16; ++i) zf[i] = 0.f;

  float16v acc0 = zf, acc1 = zf;
  float lac = 0.f;
  short8 qf[4];

  // direct fp32 Q read + scale + RNE convert (identical math to old prepass)
  auto loadQ = [&](int s) {
    const float scl = 0.125f * 1.44269504089f;   // 1/sqrt(64) * log2(e)
    const float* qp = Qp + ((size_t)bh * kS + (size_t)(s * 32 + l31)) * kD + h * 8;
    #pragma unroll
    for (int dk = 0; dk < 4; ++dk) {
      float4v a = *(const float4v*)(qp + dk * 16);
      float4v b = *(const float4v*)(qp + dk * 16 + 4);
      #pragma unroll
      for (int i = 0; i < 4; ++i) { a[i] *= scl; b[i] *= scl; }
      qf[dk] = pack8(a, b);
    }
  };

  auto unitCompute = [&](int k, int sdiag) {
    const u16* kp = gk + (size_t)k * 2048;
    const u16* vp = gv + (size_t)k * 2048;
    short8 kf[4], vf[4];
    #pragma unroll
    for (int i = 0; i < 4; ++i) kf[i] = *(const short8*)(kp + i * 512);
    #pragma unroll
    for (int i = 0; i < 4; ++i) vf[i] = *(const short8*)(vp + i * 512);

    // S^T = K * Q^T (rows = keys, cols = q)
    __builtin_amdgcn_s_setprio(1);
    float16v sv = __builtin_amdgcn_mfma_f32_32x32x16_bf16(kf[0], qf[0], zf, 0, 0, 0);
    sv = __builtin_amdgcn_mfma_f32_32x32x16_bf16(kf[1], qf[1], sv, 0, 0, 0);
    sv = __builtin_amdgcn_mfma_f32_32x32x16_bf16(kf[2], qf[2], sv, 0, 0, 0);
    sv = __builtin_amdgcn_mfma_f32_32x32x16_bf16(kf[3], qf[3], sv, 0, 0, 0);
    __builtin_amdgcn_s_setprio(0);

    if (k == sdiag) {   // diagonal subtile
      const int qg = sdiag * 32 + l31;
      #pragma unroll
      for (int r = 0; r < 16; ++r) {
        const int kg = k * 32 + (r & 3) + 8 * (r >> 2) + 4 * h;
        if (kg > qg) sv[r] = -1e30f;
      }
    }

    // p = exp2(s), pack (truncate) via v_perm
    u32 pk[8];
    #pragma unroll
    for (int g2 = 0; g2 < 4; ++g2) {
      const u32 u0 = __float_as_uint(__builtin_amdgcn_exp2f(sv[4 * g2 + 0]));
      const u32 u1 = __float_as_uint(__builtin_amdgcn_exp2f(sv[4 * g2 + 1]));
      const u32 u2 = __float_as_uint(__builtin_amdgcn_exp2f(sv[4 * g2 + 2]));
      const u32 u3 = __float_as_uint(__builtin_amdgcn_exp2f(sv[4 * g2 + 3]));
      pk[2 * g2]     = __builtin_amdgcn_perm(u1, u0, 0x07060302u);
      pk[2 * g2 + 1] = __builtin_amdgcn_perm(u3, u2, 0x07060302u);
    }

    // l partial: 2-accumulator sum of this lane's 16 bf16-truncated P values
    {
      float e0 = 0.f, e1 = 0.f;
      #pragma unroll
      for (int i = 0; i < 4; ++i) {
        e0 += __uint_as_float(pk[i] << 16)     + __uint_as_float(pk[i] & 0xFFFF0000u);
        e1 += __uint_as_float(pk[i + 4] << 16) + __uint_as_float(pk[i + 4] & 0xFFFF0000u);
      }
      lac += e0 + e1;
    }

    // exchange partner half via permlane32_swap; PV MFMA
    union { u32 u[4]; short8 s8; } pf;
    swap32(pk[0], pk[2], pf.u[0], pf.u[2]);
    swap32(pk[1], pk[3], pf.u[1], pf.u[3]);
    __builtin_amdgcn_s_setprio(1);
    acc0 = __builtin_amdgcn_mfma_f32_32x32x16_bf16(pf.s8, vf[0], acc0, 0, 0, 0);
    acc1 = __builtin_amdgcn_mfma_f32_32x32x16_bf16(pf.s8, vf[1], acc1, 0, 0, 0);
    __builtin_amdgcn_s_setprio(0);
    swap32(pk[4], pk[6], pf.u[0], pf.u[2]);
    swap32(pk[5], pk[7], pf.u[1], pf.u[3]);
    __builtin_amdgcn_s_setprio(1);
    acc0 = __builtin_amdgcn_mfma_f32_32x32x16_bf16(pf.s8, vf[2], acc0, 0, 0, 0);
    acc1 = __builtin_amdgcn_mfma_f32_32x32x16_bf16(pf.s8, vf[3], acc1, 0, 0, 0);
    __builtin_amdgcn_s_setprio(0);
  };

  auto dump = [&](int slot) {
    #pragma unroll
    for (int r = 0; r < 16; ++r) {
      const int row = (r & 3) + 8 * (r >> 2) + 4 * h;
      ldsP[slot][row][l31] = (u32)f2bf(acc0[r]) | ((u32)f2bf(acc1[r]) << 16);
    }
    const float lt = lac + __shfl_xor(lac, 32);
    if (lane < 32) ldsL[slot][lane] = lt;
  };

  // ---- phase B: set sB, units [lo, uT) with k = u ----
  if (lo < uT) {
    loadQ(sB);
    for (int u = lo; u < uT; ++u) unitCompute(u, sB);
    dump(wave);
    acc0 = zf; acc1 = zf; lac = 0.f;
  }
  // ---- phase A: set sA, units [uT, hi) with k = u - t ----
  if (uT < hi) {
    loadQ(sA);
    for (int u = uT; u < hi; ++u) unitCompute(u - t, sA);
    dump((lo < uT) ? 4 : wave);
  }

  __syncthreads();

  // ---- in-block reduce: 2 sets x 32 q x 64 d; thread covers 8 packed u32 ----
  {
    const int setid = tid >> 7;          // 0 => B, 1 => A
    const int sOut  = setid ? sA : sB;
    // slot validity per set (chunk lows 0,16,32,48; t in [33,64])
    const bool v0 = setid ? (0  >= t) : (0  < t);
    const bool v1 = setid ? (16 >= t) : (16 < t);
    const bool v2 = setid ? (32 >= t) : (32 < t);
    const bool v3 = setid ? (48 >= t) : (48 < t);
    const bool v4 = (setid != 0) && (t != 48);   // transition partial is A

    const int q  = (tid & 127) >> 2;
    const int c0 = (tid & 3) * 8;

    float lsum = 0.f;
    if (v0) lsum += ldsL[0][q];
    if (v1) lsum += ldsL[1][q];
    if (v2) lsum += ldsL[2][q];
    if (v3) lsum += ldsL[3][q];
    if (v4) lsum += ldsL[4][q];
    const float inv = 1.f / lsum;

    float* op = O + ((size_t)bh * kS + sOut * 32 + q) * kD;
    #pragma unroll
    for (int i = 0; i < 8; ++i) {
      const int c = c0 + i;
      float lov = 0.f, hiv = 0.f;
      if (v0) { const u32 p = ldsP[0][q][c]; lov += __uint_as_float(p << 16); hiv += __uint_as_float(p & 0xFFFF0000u); }
      if (v1) { const u32 p = ldsP[1][q][c]; lov += __uint_as_float(p << 16); hiv += __uint_as_float(p & 0xFFFF0000u); }
      if (v2) { const u32 p = ldsP[2][q][c]; lov += __uint_as_float(p << 16); hiv += __uint_as_float(p & 0xFFFF0000u); }
      if (v3) { const u32 p = ldsP[3][q][c]; lov += __uint_as_float(p << 16); hiv += __uint_as_float(p & 0xFFFF0000u); }
      if (v4) { const u32 p = ldsP[4][q][c]; lov += __uint_as_float(p << 16); hiv += __uint_as_float(p & 0xFFFF0000u); }
      op[c]      = lov * inv;
      op[c + 32] = hiv * inv;
    }
  }
}

extern "C" void kernel_launch(void* const* d_in, const int* in_sizes, int n_in,
                              void* d_out, int out_size, void* d_ws, size_t ws_size,
                              hipStream_t stream) {
  const float* Q = (const float*)d_in[0];
  const float* K = (const float*)d_in[1];
  const float* V = (const float*)d_in[2];
  float* O = (float*)d_out;

  const size_t nKV = (size_t)kBH * kS * kD;      // 4.19M elems
  u16* Kf = (u16*)d_ws;                          // 8.39 MB
  u16* Vf = Kf + nKV;                            // 8.39 MB

  dim3 gprep(kS / 64, kBH);
  prep_kernel<<<gprep, 256, 0, stream>>>(K, V, Kf, Vf);
  fattn_kernel<<<1024, 256, 0, stream>>>(Q, Kf, Vf, O);
}